// Round 18
// baseline (169.387 us; speedup 1.0000x reference)
//
#include <hip/hip_runtime.h>
#include <hip/hip_bf16.h>
#include <hip/hip_fp16.h>
#include <math.h>

#define NEG_SLOPE 0.2f
#define GAT_EPS 1e-16f
#define NBB_MAX 128        // buckets of 1024 dsts: N <= 131072 (src fits 17 bits)
#define CAP   19456        // per-bucket capacity (mean 17408, +15 sigma)

// ---------------- gemm1 path (device fn): h1 = X@W1 fp16 + scores ------------
__device__ __forceinline__ void gemm1_path(
    int gid, int N,
    const float* __restrict__ x, const float* __restrict__ W1,
    const float* __restrict__ a_src, const float* __restrict__ a_dst,
    __half* __restrict__ h1, float* __restrict__ s_src, float* __restrict__ s_dst)
{
    int n = gid >> 5;
    int j4 = gid & 31;
    if (n >= N) return;
    const float4* xr = (const float4*)(x + (size_t)n * 16);
    float4 x0 = xr[0], x1 = xr[1], x2 = xr[2], x3 = xr[3];
    float xs[16] = { x0.x,x0.y,x0.z,x0.w, x1.x,x1.y,x1.z,x1.w,
                     x2.x,x2.y,x2.z,x2.w, x3.x,x3.y,x3.z,x3.w };
    const float4* W4 = (const float4*)W1;   // [16][32] as float4
    float4 acc = {0.f, 0.f, 0.f, 0.f};
#pragma unroll
    for (int k = 0; k < 16; ++k) {
        float4 w = W4[k * 32 + j4];
        acc.x += xs[k] * w.x;
        acc.y += xs[k] * w.y;
        acc.z += xs[k] * w.z;
        acc.w += xs[k] * w.w;
    }
    union { __half2 h2v[2]; uint2 u; } pk;
    pk.h2v[0] = __floats2half2_rn(acc.x, acc.y);
    pk.h2v[1] = __floats2half2_rn(acc.z, acc.w);
    ((uint2*)h1)[(size_t)n * 32 + j4] = pk.u;
    float4 av = ((const float4*)a_src)[j4];
    float4 dv = ((const float4*)a_dst)[j4];
    float ps = acc.x*av.x + acc.y*av.y + acc.z*av.z + acc.w*av.w;
    float pd = acc.x*dv.x + acc.y*dv.y + acc.z*dv.z + acc.w*dv.w;
    ps += __shfl_xor(ps, 1); ps += __shfl_xor(ps, 2);
    pd += __shfl_xor(pd, 1); pd += __shfl_xor(pd, 2);
    if ((j4 & 3) == 0) {
        int h = j4 >> 2;
        s_src[n * 8 + h] = ps;
        s_dst[n * 8 + h] = pd;
    }
}

// ---------------- D1: fused [part blocks | gemmA blocks], 1024 thr -----------
__global__ __launch_bounds__(1024) void k_partgemm(
    const int* __restrict__ ei, int E, int N, int NB, int G2,
    int* __restrict__ cnt, unsigned int* __restrict__ bp,
    const float* __restrict__ x, const float* __restrict__ W1,
    const float* __restrict__ a_src, const float* __restrict__ a_dst,
    __half* __restrict__ h1, float* __restrict__ s_src, float* __restrict__ s_dst)
{
    __shared__ int hist[NBB_MAX];
    __shared__ int base[NBB_MAX];
    int t = threadIdx.x;
    if (blockIdx.x >= G2) {
        gemm1_path((blockIdx.x - G2) * 1024 + t, N,
                   x, W1, a_src, a_dst, h1, s_src, s_dst);
        return;
    }
    int e0 = blockIdx.x * 4096;
    int srcs[4], dsts[4];
#pragma unroll
    for (int k = 0; k < 4; ++k) {
        int e = e0 + k * 1024 + t;
        if (e < E + N) {
            if (e < E) { srcs[k] = ei[e]; dsts[k] = ei[E + e]; }
            else       { srcs[k] = dsts[k] = e - E; }
        } else dsts[k] = -1;
    }
    if (t < NB) hist[t] = 0;
    __syncthreads();
#pragma unroll
    for (int k = 0; k < 4; ++k)
        if (dsts[k] >= 0) atomicAdd(&hist[dsts[k] >> 10], 1);
    __syncthreads();
    if (t < NB) {
        int c = hist[t];
        base[t] = (c > 0) ? atomicAdd(&cnt[t], c) : 0;
        hist[t] = 0;
    }
    __syncthreads();
#pragma unroll
    for (int k = 0; k < 4; ++k) {
        if (dsts[k] >= 0) {
            int b = dsts[k] >> 10;
            int r = base[b] + atomicAdd(&hist[b], 1);
            if (r < CAP)   // safety clamp (+15 sigma headroom, never expected)
                bp[(size_t)b * CAP + r] =
                    ((unsigned)(dsts[k] & 1023) << 17) | (unsigned)srcs[k];
        }
    }
}

// ---------------- D2: fused [csr blocks | gemmB blocks], 1024 thr ------------
__global__ __launch_bounds__(1024) void k_csrgemm(
    const unsigned int* __restrict__ bp, const int* __restrict__ cnt,
    int* __restrict__ offs, int* __restrict__ ends, int* __restrict__ csr,
    int N, int NB, int gemmOff,
    const float* __restrict__ x, const float* __restrict__ W1,
    const float* __restrict__ a_src, const float* __restrict__ a_dst,
    __half* __restrict__ h1, float* __restrict__ s_src, float* __restrict__ s_dst)
{
    __shared__ int dcount[1024];
    __shared__ int dtmp[1024];
    __shared__ int doff[1024];
    int t = threadIdx.x;
    if (blockIdx.x >= NB) {
        gemm1_path((blockIdx.x - NB) * 1024 + t + gemmOff, N,
                   x, W1, a_src, a_dst, h1, s_src, s_dst);
        return;
    }
    int b = blockIdx.x;
    int rb = b * CAP;
    int m = cnt[b]; if (m > CAP) m = CAP;
    dcount[t] = 0;
    __syncthreads();
    for (int i = t; i < m; i += 1024)
        atomicAdd(&dcount[bp[rb + i] >> 17], 1);
    __syncthreads();
    int v = dcount[t];
    dtmp[t] = v;
    __syncthreads();
    for (int off = 1; off < 1024; off <<= 1) {
        int add = (t >= off) ? dtmp[t - off] : 0;
        __syncthreads();
        dtmp[t] += add;
        __syncthreads();
    }
    doff[t] = dtmp[t] - v;          // exclusive within bucket
    int n = b * 1024 + t;
    if (n < N) { offs[n] = rb + doff[t]; ends[n] = rb + dtmp[t]; }
    dcount[t] = 0;                  // reuse as scatter cursor
    __syncthreads();
    for (int i = t; i < m; i += 1024) {
        unsigned int p = bp[rb + i];
        int dl = p >> 17;
        int r = atomicAdd(&dcount[dl], 1);
        csr[rb + doff[dl] + r] = (int)(p & 0x1FFFFu);
    }
}

// ---------------- K5: fused layer-1 aggregate + ReLU + layer-2 node ----------
// 16 threads per dst: t = (half<<3)|h. 4-edge unroll (8 gathers in flight).
__global__ __launch_bounds__(256) void k_agg1(
    const __half* __restrict__ h1, const float* __restrict__ s_src,
    const float* __restrict__ s_dst, const float* __restrict__ b1,
    const float* __restrict__ W2, const float* __restrict__ a_src2,
    const float* __restrict__ a_dst2,
    const int* __restrict__ offs, const int* __restrict__ ends,
    const int* __restrict__ csr_src,
    float4* __restrict__ h2packed, float* __restrict__ s2d, int N)
{
    int gid = blockIdx.x * 256 + threadIdx.x;
    if (gid >= N * 16) return;
    int n = gid >> 4;
    int t = gid & 15;
    int h = t & 7;
    int half = t >> 3;
    int beg = offs[n], end = ends[n];
    float sd = s_dst[n * 8 + h];

    float z = 0.f;
    float acc[16];
#pragma unroll
    for (int c = 0; c < 16; ++c) acc[c] = 0.f;

    union U { float4 f; __half2 hh[4]; };
    int i = beg + half;
    // 4-edge unrolled loop (edges i, i+2, i+4, i+6)
    for (; i + 6 < end; i += 8) {
        int s0 = csr_src[i];
        int s1 = csr_src[i + 2];
        int s2 = csr_src[i + 4];
        int s3 = csr_src[i + 6];
        const float4* p0 = (const float4*)(h1 + (size_t)s0 * 128 + h * 16);
        const float4* p1 = (const float4*)(h1 + (size_t)s1 * 128 + h * 16);
        const float4* p2 = (const float4*)(h1 + (size_t)s2 * 128 + h * 16);
        const float4* p3 = (const float4*)(h1 + (size_t)s3 * 128 + h * 16);
        U a0, a1, b0, b1v, c0, c1, d0, d1;
        a0.f = p0[0]; a1.f = p0[1];
        b0.f = p1[0]; b1v.f = p1[1];
        c0.f = p2[0]; c1.f = p2[1];
        d0.f = p3[0]; d1.f = p3[1];
        float e0 = s_src[s0 * 8 + h] + sd;
        float e1 = s_src[s1 * 8 + h] + sd;
        float e2 = s_src[s2 * 8 + h] + sd;
        float e3 = s_src[s3 * 8 + h] + sd;
        e0 = (e0 > 0.f) ? e0 : NEG_SLOPE * e0;
        e1 = (e1 > 0.f) ? e1 : NEG_SLOPE * e1;
        e2 = (e2 > 0.f) ? e2 : NEG_SLOPE * e2;
        e3 = (e3 > 0.f) ? e3 : NEG_SLOPE * e3;
        float q0 = __expf(e0), q1 = __expf(e1);
        float q2 = __expf(e2), q3 = __expf(e3);
        z += (q0 + q1) + (q2 + q3);
#pragma unroll
        for (int k = 0; k < 4; ++k) {
            float2 vA = __half22float2(a0.hh[k]);
            float2 vB = __half22float2(b0.hh[k]);
            float2 vC = __half22float2(c0.hh[k]);
            float2 vD = __half22float2(d0.hh[k]);
            acc[2 * k]     += q0 * vA.x + q1 * vB.x + q2 * vC.x + q3 * vD.x;
            acc[2 * k + 1] += q0 * vA.y + q1 * vB.y + q2 * vC.y + q3 * vD.y;
        }
#pragma unroll
        for (int k = 0; k < 4; ++k) {
            float2 vA = __half22float2(a1.hh[k]);
            float2 vB = __half22float2(b1v.hh[k]);
            float2 vC = __half22float2(c1.hh[k]);
            float2 vD = __half22float2(d1.hh[k]);
            acc[8 + 2 * k] += q0 * vA.x + q1 * vB.x + q2 * vC.x + q3 * vD.x;
            acc[9 + 2 * k] += q0 * vA.y + q1 * vB.y + q2 * vC.y + q3 * vD.y;
        }
    }
    // 2-edge loop
    for (; i + 2 < end; i += 4) {
        int sA = csr_src[i];
        int sB = csr_src[i + 2];
        const float4* hA = (const float4*)(h1 + (size_t)sA * 128 + h * 16);
        const float4* hB = (const float4*)(h1 + (size_t)sB * 128 + h * 16);
        U a0, a1, b0, b1v;
        a0.f = hA[0]; a1.f = hA[1];
        b0.f = hB[0]; b1v.f = hB[1];
        float eA = s_src[sA * 8 + h] + sd;
        float eB = s_src[sB * 8 + h] + sd;
        eA = (eA > 0.f) ? eA : NEG_SLOPE * eA;
        eB = (eB > 0.f) ? eB : NEG_SLOPE * eB;
        float pA = __expf(eA);
        float pB = __expf(eB);
        z += pA + pB;
#pragma unroll
        for (int k = 0; k < 4; ++k) {
            float2 vA = __half22float2(a0.hh[k]);
            float2 vB = __half22float2(b0.hh[k]);
            acc[2 * k]     += pA * vA.x + pB * vB.x;
            acc[2 * k + 1] += pA * vA.y + pB * vB.y;
        }
#pragma unroll
        for (int k = 0; k < 4; ++k) {
            float2 vA = __half22float2(a1.hh[k]);
            float2 vB = __half22float2(b1v.hh[k]);
            acc[8 + 2 * k] += pA * vA.x + pB * vB.x;
            acc[9 + 2 * k] += pA * vA.y + pB * vB.y;
        }
    }
    if (i < end) {
        int sA = csr_src[i];
        const float4* hA = (const float4*)(h1 + (size_t)sA * 128 + h * 16);
        U a0, a1;
        a0.f = hA[0]; a1.f = hA[1];
        float eA = s_src[sA * 8 + h] + sd;
        eA = (eA > 0.f) ? eA : NEG_SLOPE * eA;
        float pA = __expf(eA);
        z += pA;
#pragma unroll
        for (int k = 0; k < 4; ++k) {
            float2 vA = __half22float2(a0.hh[k]);
            acc[2 * k]     += pA * vA.x;
            acc[2 * k + 1] += pA * vA.y;
        }
#pragma unroll
        for (int k = 0; k < 4; ++k) {
            float2 vA = __half22float2(a1.hh[k]);
            acc[8 + 2 * k] += pA * vA.x;
            acc[9 + 2 * k] += pA * vA.y;
        }
    }

    z += __shfl_xor(z, 8);
#pragma unroll
    for (int c = 0; c < 16; ++c) acc[c] += __shfl_xor(acc[c], 8);

    float inv = 1.f / (z + GAT_EPS);

    float r0 = 0.f, r1 = 0.f, r2 = 0.f;
    const float* bb = b1 + h * 16;
    const float* w2 = W2 + h * 16 * 3;
#pragma unroll
    for (int c = 0; c < 16; ++c) {
        float xc = fmaxf(acc[c] * inv + bb[c], 0.f);
        r0 += xc * w2[c * 3 + 0];
        r1 += xc * w2[c * 3 + 1];
        r2 += xc * w2[c * 3 + 2];
    }
#pragma unroll
    for (int m = 4; m >= 1; m >>= 1) {
        r0 += __shfl_xor(r0, m);
        r1 += __shfl_xor(r1, m);
        r2 += __shfl_xor(r2, m);
    }
    if (t == 0) {
        float ss = r0 * a_src2[0] + r1 * a_src2[1] + r2 * a_src2[2];
        float dd = r0 * a_dst2[0] + r1 * a_dst2[1] + r2 * a_dst2[2];
        float4 pk = { r0, r1, r2, ss };
        h2packed[n] = pk;
        s2d[n] = dd;
    }
}

// ---------------- K6: layer-2 aggregate -> out. 8 threads per dst ------------
__global__ __launch_bounds__(256) void k_agg2(
    const float4* __restrict__ h2packed, const float* __restrict__ s2d,
    const float* __restrict__ b2,
    const int* __restrict__ offs, const int* __restrict__ ends,
    const int* __restrict__ csr_src,
    float* __restrict__ out, int N)
{
    int gid = blockIdx.x * 256 + threadIdx.x;
    if (gid >= N * 8) return;
    int n = gid >> 3;
    int t = gid & 7;
    int beg = offs[n], end = ends[n];
    float sd = s2d[n];
    float z = 0.f, a0 = 0.f, a1 = 0.f, a2 = 0.f;
    for (int i = beg + t; i < end; i += 8) {
        int src = csr_src[i];
        float4 v = h2packed[src];
        float s = v.w + sd;
        s = (s > 0.f) ? s : NEG_SLOPE * s;
        float p = __expf(s);
        z += p;
        a0 += p * v.x; a1 += p * v.y; a2 += p * v.z;
    }
#pragma unroll
    for (int m = 4; m >= 1; m >>= 1) {
        z  += __shfl_xor(z, m);
        a0 += __shfl_xor(a0, m);
        a1 += __shfl_xor(a1, m);
        a2 += __shfl_xor(a2, m);
    }
    if (t == 0) {
        float inv = 1.f / (z + GAT_EPS);
        out[(size_t)n * 3 + 0] = a0 * inv + b2[0];
        out[(size_t)n * 3 + 1] = a1 * inv + b2[1];
        out[(size_t)n * 3 + 2] = a2 * inv + b2[2];
    }
}

extern "C" void kernel_launch(void* const* d_in, const int* in_sizes, int n_in,
                              void* d_out, int out_size, void* d_ws, size_t ws_size,
                              hipStream_t stream)
{
    const float* feature = (const float*)d_in[0];
    const int*   ei      = (const int*)d_in[1];
    // d_in[2] edge_type: unused by reference
    const float* W1      = (const float*)d_in[3];
    const float* a_src1  = (const float*)d_in[4];
    const float* a_dst1  = (const float*)d_in[5];
    const float* b1      = (const float*)d_in[6];
    const float* W2      = (const float*)d_in[7];
    const float* a_src2  = (const float*)d_in[8];
    const float* a_dst2  = (const float*)d_in[9];
    const float* b2      = (const float*)d_in[10];

    const int N = in_sizes[0] / 16;
    const int E = in_sizes[1] / 2;
    const int ET = E + N;
    const int NB = (N + 1023) >> 10;        // 98 for N=100000 (<= NBB_MAX)

    char* p = (char*)d_ws;
    auto alloc = [&](size_t bytes) -> void* {
        void* r = (void*)p;
        p += (bytes + 255) & ~(size_t)255;
        return r;
    };
    __half* h1   = (__half*)alloc((size_t)N * 128 * 2);
    float*  s1s  = (float*)alloc((size_t)N * 8 * 4);
    float*  s1d  = (float*)alloc((size_t)N * 8 * 4);
    float4* h2pk = (float4*)alloc((size_t)N * 16);
    float*  s2dv = (float*)alloc((size_t)N * 4);
    int*    offs = (int*)alloc((size_t)N * 4);
    int*    ends = (int*)alloc((size_t)N * 4);
    int*    csr  = (int*)alloc((size_t)NB * CAP * 4);
    unsigned int* bp = (unsigned int*)alloc((size_t)NB * CAP * 4);
    int*    cnt  = (int*)alloc((size_t)NBB_MAX * 4);

    hipMemsetAsync(cnt, 0, (size_t)NB * 4, stream);

    // gemm split across the two prep dispatches
    int G2 = (ET + 4095) / 4096;            // part blocks
    int G1 = (N * 32 + 1023) / 1024;        // total gemm blocks
    int G1A = (G1 + 1) / 2;                 // in dispatch 1
    int G1B = G1 - G1A;                     // in dispatch 2

    // D1: edge partition || gemm (first half)
    k_partgemm<<<G2 + G1A, 1024, 0, stream>>>(
        ei, E, N, NB, G2, cnt, bp,
        feature, W1, a_src1, a_dst1, h1, s1s, s1d);

    // D2: CSR build || gemm (second half)
    k_csrgemm<<<NB + G1B, 1024, 0, stream>>>(
        bp, cnt, offs, ends, csr, N, NB, G1A * 1024,
        feature, W1, a_src1, a_dst1, h1, s1s, s1d);

    // fused layer-1 aggregation + layer-2 node transform (16 thr/dst)
    k_agg1<<<(N * 16 + 255) / 256, 256, 0, stream>>>(
        h1, s1s, s1d, b1, W2, a_src2, a_dst2, offs, ends, csr, h2pk, s2dv, N);

    // layer-2 aggregation -> out
    k_agg2<<<(N * 8 + 255) / 256, 256, 0, stream>>>(
        h2pk, s2dv, b2, offs, ends, csr, (float*)d_out, N);
}

// Round 19
// 167.483 us; speedup vs baseline: 1.0114x; 1.0114x over previous
//
#include <hip/hip_runtime.h>
#include <hip/hip_bf16.h>
#include <hip/hip_fp16.h>
#include <math.h>

#define NEG_SLOPE 0.2f
#define GAT_EPS 1e-16f
#define NBMAX 256          // buckets of 512 dsts: N <= 131072 (src fits 17 bits)
#define CAP   9728         // per-bucket capacity (mean 8704, +11 sigma)

// ---------------- K1: partition via block-local counting sort ----------------
// 4096 edges/block. LDS: hist->scan->bucket-sorted buffer->coalesced sweep-out.
// Consecutive threads write consecutive addresses of each run -> full lines.
__global__ __launch_bounds__(1024) void k_part(
    const int* __restrict__ ei, int E, int N, int NB,
    int* __restrict__ cnt, unsigned int* __restrict__ bp)
{
    __shared__ unsigned int buf[4096];
    __shared__ unsigned short bkt[4096];
    __shared__ int hist[NBMAX];
    __shared__ int dtmp[NBMAX];
    __shared__ int loff[NBMAX];
    __shared__ int gbase[NBMAX];
    int t = threadIdx.x;
    int e0 = blockIdx.x * 4096;
    int ntot = E + N;
    int nblk = ntot - e0; if (nblk > 4096) nblk = 4096;
    int srcs[4], dsts[4];
#pragma unroll
    for (int k = 0; k < 4; ++k) {
        int e = e0 + k * 1024 + t;
        if (e < ntot) {
            if (e < E) { srcs[k] = ei[e]; dsts[k] = ei[E + e]; }
            else       { srcs[k] = dsts[k] = e - E; }
        } else dsts[k] = -1;
    }
    if (t < NB) hist[t] = 0;
    __syncthreads();
#pragma unroll
    for (int k = 0; k < 4; ++k)
        if (dsts[k] >= 0) atomicAdd(&hist[dsts[k] >> 9], 1);
    __syncthreads();
    int v = 0;
    if (t < NB) { v = hist[t]; dtmp[t] = v; }
    __syncthreads();
    for (int off = 1; off < NBMAX; off <<= 1) {
        int add = (t < NB && t >= off) ? dtmp[t - off] : 0;
        __syncthreads();
        if (t < NB) dtmp[t] += add;
        __syncthreads();
    }
    if (t < NB) {
        loff[t] = dtmp[t] - v;              // block-local exclusive offset
        gbase[t] = (v > 0) ? atomicAdd(&cnt[t], v) : 0;
        hist[t] = 0;                        // reuse as rank cursor
    }
    __syncthreads();
#pragma unroll
    for (int k = 0; k < 4; ++k) {
        if (dsts[k] >= 0) {
            int b = dsts[k] >> 9;
            int r = atomicAdd(&hist[b], 1);
            int pos = loff[b] + r;
            buf[pos] = ((unsigned)(dsts[k] & 511) << 17) | (unsigned)srcs[k];
            bkt[pos] = (unsigned short)b;
        }
    }
    __syncthreads();
    for (int i = t; i < nblk; i += 1024) {
        int b = bkt[i];
        int gpos = gbase[b] + (i - loff[b]);
        if (gpos < CAP)    // safety clamp (+11 sigma headroom, never expected)
            bp[(size_t)b * CAP + gpos] = buf[i];
    }
}

// ---------------- gemm1 path (device fn): h1 = X@W1 fp16 + scores ------------
__device__ __forceinline__ void gemm1_path(
    int gid, int N,
    const float* __restrict__ x, const float* __restrict__ W1,
    const float* __restrict__ a_src, const float* __restrict__ a_dst,
    __half* __restrict__ h1, float* __restrict__ s_src, float* __restrict__ s_dst)
{
    int n = gid >> 5;
    int j4 = gid & 31;
    if (n >= N) return;
    const float4* xr = (const float4*)(x + (size_t)n * 16);
    float4 x0 = xr[0], x1 = xr[1], x2 = xr[2], x3 = xr[3];
    float xs[16] = { x0.x,x0.y,x0.z,x0.w, x1.x,x1.y,x1.z,x1.w,
                     x2.x,x2.y,x2.z,x2.w, x3.x,x3.y,x3.z,x3.w };
    const float4* W4 = (const float4*)W1;   // [16][32] as float4
    float4 acc = {0.f, 0.f, 0.f, 0.f};
#pragma unroll
    for (int k = 0; k < 16; ++k) {
        float4 w = W4[k * 32 + j4];
        acc.x += xs[k] * w.x;
        acc.y += xs[k] * w.y;
        acc.z += xs[k] * w.z;
        acc.w += xs[k] * w.w;
    }
    union { __half2 h2v[2]; uint2 u; } pk;
    pk.h2v[0] = __floats2half2_rn(acc.x, acc.y);
    pk.h2v[1] = __floats2half2_rn(acc.z, acc.w);
    ((uint2*)h1)[(size_t)n * 32 + j4] = pk.u;
    float4 av = ((const float4*)a_src)[j4];
    float4 dv = ((const float4*)a_dst)[j4];
    float ps = acc.x*av.x + acc.y*av.y + acc.z*av.z + acc.w*av.w;
    float pd = acc.x*dv.x + acc.y*dv.y + acc.z*dv.z + acc.w*dv.w;
    ps += __shfl_xor(ps, 1); ps += __shfl_xor(ps, 2);
    pd += __shfl_xor(pd, 1); pd += __shfl_xor(pd, 2);
    if ((j4 & 3) == 0) {
        int h = j4 >> 2;
        s_src[n * 8 + h] = ps;
        s_dst[n * 8 + h] = pd;
    }
}

// ---------------- D2: fused [csr blocks | gemm blocks], 1024 thr -------------
__global__ __launch_bounds__(1024) void k_csrgemm(
    const unsigned int* __restrict__ bp, const int* __restrict__ cnt,
    int* __restrict__ offs, int* __restrict__ ends, int* __restrict__ csr,
    int N, int NB,
    const float* __restrict__ x, const float* __restrict__ W1,
    const float* __restrict__ a_src, const float* __restrict__ a_dst,
    __half* __restrict__ h1, float* __restrict__ s_src, float* __restrict__ s_dst)
{
    __shared__ int dcount[512];
    __shared__ int dtmp[512];
    __shared__ int doff[512];
    int t = threadIdx.x;
    if (blockIdx.x >= NB) {
        gemm1_path((blockIdx.x - NB) * 1024 + t, N,
                   x, W1, a_src, a_dst, h1, s_src, s_dst);
        return;
    }
    int b = blockIdx.x;
    int rb = b * CAP;
    int m = cnt[b]; if (m > CAP) m = CAP;
    if (t < 512) dcount[t] = 0;
    __syncthreads();
    for (int i = t; i < m; i += 1024)
        atomicAdd(&dcount[bp[rb + i] >> 17], 1);
    __syncthreads();
    int v = 0;
    if (t < 512) { v = dcount[t]; dtmp[t] = v; }
    __syncthreads();
    for (int off = 1; off < 512; off <<= 1) {
        int add = (t < 512 && t >= off) ? dtmp[t - off] : 0;
        __syncthreads();
        if (t < 512) dtmp[t] += add;
        __syncthreads();
    }
    if (t < 512) {
        doff[t] = dtmp[t] - v;          // exclusive within bucket
        int n = b * 512 + t;
        if (n < N) { offs[n] = rb + doff[t]; ends[n] = rb + dtmp[t]; }
        dcount[t] = 0;                  // reuse as scatter cursor
    }
    __syncthreads();
    for (int i = t; i < m; i += 1024) {
        unsigned int p = bp[rb + i];
        int dl = p >> 17;
        int r = atomicAdd(&dcount[dl], 1);
        csr[rb + doff[dl] + r] = (int)(p & 0x1FFFFu);
    }
}

// ---------------- K5: fused layer-1 aggregate + ReLU + layer-2 node ----------
// 16 threads per dst: t = (half<<3)|h. 4-edge unroll (8 gathers in flight).
__global__ __launch_bounds__(256) void k_agg1(
    const __half* __restrict__ h1, const float* __restrict__ s_src,
    const float* __restrict__ s_dst, const float* __restrict__ b1,
    const float* __restrict__ W2, const float* __restrict__ a_src2,
    const float* __restrict__ a_dst2,
    const int* __restrict__ offs, const int* __restrict__ ends,
    const int* __restrict__ csr_src,
    float4* __restrict__ h2packed, float* __restrict__ s2d, int N)
{
    int gid = blockIdx.x * 256 + threadIdx.x;
    if (gid >= N * 16) return;
    int n = gid >> 4;
    int t = gid & 15;
    int h = t & 7;
    int half = t >> 3;
    int beg = offs[n], end = ends[n];
    float sd = s_dst[n * 8 + h];

    float z = 0.f;
    float acc[16];
#pragma unroll
    for (int c = 0; c < 16; ++c) acc[c] = 0.f;

    union U { float4 f; __half2 hh[4]; };
    int i = beg + half;
    for (; i + 6 < end; i += 8) {
        int s0 = csr_src[i];
        int s1 = csr_src[i + 2];
        int s2 = csr_src[i + 4];
        int s3 = csr_src[i + 6];
        const float4* p0 = (const float4*)(h1 + (size_t)s0 * 128 + h * 16);
        const float4* p1 = (const float4*)(h1 + (size_t)s1 * 128 + h * 16);
        const float4* p2 = (const float4*)(h1 + (size_t)s2 * 128 + h * 16);
        const float4* p3 = (const float4*)(h1 + (size_t)s3 * 128 + h * 16);
        U a0, a1, b0, b1v, c0, c1, d0, d1;
        a0.f = p0[0]; a1.f = p0[1];
        b0.f = p1[0]; b1v.f = p1[1];
        c0.f = p2[0]; c1.f = p2[1];
        d0.f = p3[0]; d1.f = p3[1];
        float e0 = s_src[s0 * 8 + h] + sd;
        float e1 = s_src[s1 * 8 + h] + sd;
        float e2 = s_src[s2 * 8 + h] + sd;
        float e3 = s_src[s3 * 8 + h] + sd;
        e0 = (e0 > 0.f) ? e0 : NEG_SLOPE * e0;
        e1 = (e1 > 0.f) ? e1 : NEG_SLOPE * e1;
        e2 = (e2 > 0.f) ? e2 : NEG_SLOPE * e2;
        e3 = (e3 > 0.f) ? e3 : NEG_SLOPE * e3;
        float q0 = __expf(e0), q1 = __expf(e1);
        float q2 = __expf(e2), q3 = __expf(e3);
        z += (q0 + q1) + (q2 + q3);
#pragma unroll
        for (int k = 0; k < 4; ++k) {
            float2 vA = __half22float2(a0.hh[k]);
            float2 vB = __half22float2(b0.hh[k]);
            float2 vC = __half22float2(c0.hh[k]);
            float2 vD = __half22float2(d0.hh[k]);
            acc[2 * k]     += q0 * vA.x + q1 * vB.x + q2 * vC.x + q3 * vD.x;
            acc[2 * k + 1] += q0 * vA.y + q1 * vB.y + q2 * vC.y + q3 * vD.y;
        }
#pragma unroll
        for (int k = 0; k < 4; ++k) {
            float2 vA = __half22float2(a1.hh[k]);
            float2 vB = __half22float2(b1v.hh[k]);
            float2 vC = __half22float2(c1.hh[k]);
            float2 vD = __half22float2(d1.hh[k]);
            acc[8 + 2 * k] += q0 * vA.x + q1 * vB.x + q2 * vC.x + q3 * vD.x;
            acc[9 + 2 * k] += q0 * vA.y + q1 * vB.y + q2 * vC.y + q3 * vD.y;
        }
    }
    for (; i + 2 < end; i += 4) {
        int sA = csr_src[i];
        int sB = csr_src[i + 2];
        const float4* hA = (const float4*)(h1 + (size_t)sA * 128 + h * 16);
        const float4* hB = (const float4*)(h1 + (size_t)sB * 128 + h * 16);
        U a0, a1, b0, b1v;
        a0.f = hA[0]; a1.f = hA[1];
        b0.f = hB[0]; b1v.f = hB[1];
        float eA = s_src[sA * 8 + h] + sd;
        float eB = s_src[sB * 8 + h] + sd;
        eA = (eA > 0.f) ? eA : NEG_SLOPE * eA;
        eB = (eB > 0.f) ? eB : NEG_SLOPE * eB;
        float pA = __expf(eA);
        float pB = __expf(eB);
        z += pA + pB;
#pragma unroll
        for (int k = 0; k < 4; ++k) {
            float2 vA = __half22float2(a0.hh[k]);
            float2 vB = __half22float2(b0.hh[k]);
            acc[2 * k]     += pA * vA.x + pB * vB.x;
            acc[2 * k + 1] += pA * vA.y + pB * vB.y;
        }
#pragma unroll
        for (int k = 0; k < 4; ++k) {
            float2 vA = __half22float2(a1.hh[k]);
            float2 vB = __half22float2(b1v.hh[k]);
            acc[8 + 2 * k] += pA * vA.x + pB * vB.x;
            acc[9 + 2 * k] += pA * vA.y + pB * vB.y;
        }
    }
    if (i < end) {
        int sA = csr_src[i];
        const float4* hA = (const float4*)(h1 + (size_t)sA * 128 + h * 16);
        U a0, a1;
        a0.f = hA[0]; a1.f = hA[1];
        float eA = s_src[sA * 8 + h] + sd;
        eA = (eA > 0.f) ? eA : NEG_SLOPE * eA;
        float pA = __expf(eA);
        z += pA;
#pragma unroll
        for (int k = 0; k < 4; ++k) {
            float2 vA = __half22float2(a0.hh[k]);
            acc[2 * k]     += pA * vA.x;
            acc[2 * k + 1] += pA * vA.y;
        }
#pragma unroll
        for (int k = 0; k < 4; ++k) {
            float2 vA = __half22float2(a1.hh[k]);
            acc[8 + 2 * k] += pA * vA.x;
            acc[9 + 2 * k] += pA * vA.y;
        }
    }

    z += __shfl_xor(z, 8);
#pragma unroll
    for (int c = 0; c < 16; ++c) acc[c] += __shfl_xor(acc[c], 8);

    float inv = 1.f / (z + GAT_EPS);

    float r0 = 0.f, r1 = 0.f, r2 = 0.f;
    const float* bb = b1 + h * 16;
    const float* w2 = W2 + h * 16 * 3;
#pragma unroll
    for (int c = 0; c < 16; ++c) {
        float xc = fmaxf(acc[c] * inv + bb[c], 0.f);
        r0 += xc * w2[c * 3 + 0];
        r1 += xc * w2[c * 3 + 1];
        r2 += xc * w2[c * 3 + 2];
    }
#pragma unroll
    for (int m = 4; m >= 1; m >>= 1) {
        r0 += __shfl_xor(r0, m);
        r1 += __shfl_xor(r1, m);
        r2 += __shfl_xor(r2, m);
    }
    if (t == 0) {
        float ss = r0 * a_src2[0] + r1 * a_src2[1] + r2 * a_src2[2];
        float dd = r0 * a_dst2[0] + r1 * a_dst2[1] + r2 * a_dst2[2];
        float4 pk = { r0, r1, r2, ss };
        h2packed[n] = pk;
        s2d[n] = dd;
    }
}

// ---------------- K6: layer-2 aggregate -> out. 8 thr/dst, 2-unroll ----------
__global__ __launch_bounds__(256) void k_agg2(
    const float4* __restrict__ h2packed, const float* __restrict__ s2d,
    const float* __restrict__ b2,
    const int* __restrict__ offs, const int* __restrict__ ends,
    const int* __restrict__ csr_src,
    float* __restrict__ out, int N)
{
    int gid = blockIdx.x * 256 + threadIdx.x;
    if (gid >= N * 8) return;
    int n = gid >> 3;
    int t = gid & 7;
    int beg = offs[n], end = ends[n];
    float sd = s2d[n];
    float z = 0.f, a0 = 0.f, a1 = 0.f, a2 = 0.f;
    int i = beg + t;
    for (; i + 8 < end; i += 16) {
        int s0 = csr_src[i];
        int s1 = csr_src[i + 8];
        float4 v0 = h2packed[s0];
        float4 v1 = h2packed[s1];
        float e0 = v0.w + sd;
        float e1 = v1.w + sd;
        e0 = (e0 > 0.f) ? e0 : NEG_SLOPE * e0;
        e1 = (e1 > 0.f) ? e1 : NEG_SLOPE * e1;
        float p0 = __expf(e0);
        float p1 = __expf(e1);
        z += p0 + p1;
        a0 += p0 * v0.x + p1 * v1.x;
        a1 += p0 * v0.y + p1 * v1.y;
        a2 += p0 * v0.z + p1 * v1.z;
    }
    if (i < end) {
        int src = csr_src[i];
        float4 v = h2packed[src];
        float s = v.w + sd;
        s = (s > 0.f) ? s : NEG_SLOPE * s;
        float p = __expf(s);
        z += p;
        a0 += p * v.x; a1 += p * v.y; a2 += p * v.z;
    }
#pragma unroll
    for (int m = 4; m >= 1; m >>= 1) {
        z  += __shfl_xor(z, m);
        a0 += __shfl_xor(a0, m);
        a1 += __shfl_xor(a1, m);
        a2 += __shfl_xor(a2, m);
    }
    if (t == 0) {
        float inv = 1.f / (z + GAT_EPS);
        out[(size_t)n * 3 + 0] = a0 * inv + b2[0];
        out[(size_t)n * 3 + 1] = a1 * inv + b2[1];
        out[(size_t)n * 3 + 2] = a2 * inv + b2[2];
    }
}

extern "C" void kernel_launch(void* const* d_in, const int* in_sizes, int n_in,
                              void* d_out, int out_size, void* d_ws, size_t ws_size,
                              hipStream_t stream)
{
    const float* feature = (const float*)d_in[0];
    const int*   ei      = (const int*)d_in[1];
    // d_in[2] edge_type: unused by reference
    const float* W1      = (const float*)d_in[3];
    const float* a_src1  = (const float*)d_in[4];
    const float* a_dst1  = (const float*)d_in[5];
    const float* b1      = (const float*)d_in[6];
    const float* W2      = (const float*)d_in[7];
    const float* a_src2  = (const float*)d_in[8];
    const float* a_dst2  = (const float*)d_in[9];
    const float* b2      = (const float*)d_in[10];

    const int N = in_sizes[0] / 16;
    const int E = in_sizes[1] / 2;
    const int ET = E + N;
    const int NB = (N + 511) >> 9;          // 196 for N=100000 (<= NBMAX)

    char* p = (char*)d_ws;
    auto alloc = [&](size_t bytes) -> void* {
        void* r = (void*)p;
        p += (bytes + 255) & ~(size_t)255;
        return r;
    };
    __half* h1   = (__half*)alloc((size_t)N * 128 * 2);
    float*  s1s  = (float*)alloc((size_t)N * 8 * 4);
    float*  s1d  = (float*)alloc((size_t)N * 8 * 4);
    float4* h2pk = (float4*)alloc((size_t)N * 16);
    float*  s2dv = (float*)alloc((size_t)N * 4);
    int*    offs = (int*)alloc((size_t)N * 4);
    int*    ends = (int*)alloc((size_t)N * 4);
    int*    csr  = (int*)alloc((size_t)NB * CAP * 4);
    unsigned int* bp = (unsigned int*)alloc((size_t)NB * CAP * 4);
    int*    cnt  = (int*)alloc((size_t)NBMAX * 4);

    hipMemsetAsync(cnt, 0, (size_t)NB * 4, stream);

    // D1: edge partition (block-local counting sort, coalesced writes)
    int G2 = (ET + 4095) / 4096;
    k_part<<<G2, 1024, 0, stream>>>(ei, E, N, NB, cnt, bp);

    // D2: CSR build (NB blocks) || layer-1 node transform (G1 blocks)
    int G1 = (N * 32 + 1023) / 1024;
    k_csrgemm<<<NB + G1, 1024, 0, stream>>>(
        bp, cnt, offs, ends, csr, N, NB,
        feature, W1, a_src1, a_dst1, h1, s1s, s1d);

    // fused layer-1 aggregation + layer-2 node transform (16 thr/dst)
    k_agg1<<<(N * 16 + 255) / 256, 256, 0, stream>>>(
        h1, s1s, s1d, b1, W2, a_src2, a_dst2, offs, ends, csr, h2pk, s2dv, N);

    // layer-2 aggregation -> out
    k_agg2<<<(N * 8 + 255) / 256, 256, 0, stream>>>(
        h2pk, s2dv, b2, offs, ends, csr, (float*)d_out, N);
}